// Round 6
// baseline (27.340 us; speedup 1.0000x reference)
//
#include <hip/hip_runtime.h>

// KAConv: out[b,f,h,w] = sum_{c,p} P_fcp(v) / (1 + |Q_fcp(v)|),
//   v = x[b,c,h+i-1,w+j-1] (zero pad), p = i*3+j
// Shapes: x[4,16,64,64], A[16,16,9,6], Bc[16,16,9,4], out[4,16,64,64], f32.
//
// Round 6 (one change vs round 4): coefficient delivery moved off the scalar
// pipe. Per c-iteration, lanes 0..53 / 0..35 issue ONE coalesced
// global_load_dword each (90 coeffs -> 2 VGPRs), prefetched a full
// c-iteration early (latency hidden under tap compute); taps extract values
// just-in-time with v_readlane (SALU, 1 cyc, no wait). This removes the
// correlated s_load lgkmcnt stalls that r1-r5 all shared (90 dwords/c-iter
// vs ~100-SGPR file => chunked scalar loads, compulsory K$ misses).

#define BB   4
#define CIN  16
#define COUT 16
#define HH   64
#define WW   64

static __device__ __forceinline__ float rdl(float v, int k) {
    return __int_as_float(__builtin_amdgcn_readlane(__float_as_int(v), k));
}

static __device__ __forceinline__ void loadw(const float* __restrict__ xb, int c,
                                             int r0, int w, float v[4][3]) {
    const float* __restrict__ xc = xb + c * (HH * WW);
    #pragma unroll
    for (int ri = 0; ri < 4; ++ri) {
        const int hh   = r0 - 1 + ri;
        const bool okh = (hh >= 0) & (hh < HH);
        #pragma unroll
        for (int j = 0; j < 3; ++j) {
            const int wj  = w + j - 1;
            const bool ok = okh & (wj >= 0) & (wj < WW);
            v[ri][j] = ok ? xc[hh * WW + wj] : 0.0f;
        }
    }
}

__global__ __launch_bounds__(512, 4) void KAConv_kernel(
    const float* __restrict__ x,    // [B,C,H,W]
    const float* __restrict__ A,    // [F,C,9,6]
    const float* __restrict__ Bc,   // [F,C,9,4]
    float* __restrict__ out)        // [B,F,H,W]
{
    // grid = b(4) x rowtile(8) x f(16) = 512 blocks; block = 512 = 8 waves,
    // 2 teams x 256 thr; team t handles channels t*8..t*8+7, 2 px/thread.
    const int blk   = blockIdx.x;
    const int f     = blk & 15;
    const int rtile = (blk >> 4) & 7;
    const int b     = blk >> 7;

    const int tid  = threadIdx.x;
    const int team = __builtin_amdgcn_readfirstlane(tid >> 8);   // 0 or 1
    const int tp   = tid & 255;
    const int lane = tid & 63;
    const int w    = tp & 63;
    const int r0   = (rtile << 3) + ((tp >> 6) << 1);  // rows r0, r0+1
    const int c0   = team << 3;

    const float* __restrict__ xb = x  + (b * CIN + c0) * (HH * WW);
    const float* __restrict__ Af = A  + (f * CIN + c0) * 54;
    const float* __restrict__ Bf = Bc + (f * CIN + c0) * 36;

    // Per-lane coefficient slots: lane k holds A-dword k (k<54), B-dword k (k<36).
    const int laneA = lane < 54 ? lane : 53;
    const int laneB = lane < 36 ? lane : 35;

    __shared__ float sRed[2 * 256];

    // Prefetch c = 0 (coeffs via vector pipe + windows).
    float cA = Af[laneA];            // one coalesced global_load_dword (216 B)
    float cB = Bf[laneB];            // one coalesced global_load_dword (144 B)
    float vv[4][3];
    loadw(xb, 0, r0, w, vv);

    float acc0 = 0.0f, acc1 = 0.0f;

    #pragma unroll 1
    for (int c = 0; c < 8; ++c) {
        // Prefetch next c (clamped on last iter; harmless duplicate loads).
        const int cn = (c + 1 < 8) ? c + 1 : 7;
        float nA = Af[cn * 54 + laneA];
        float nB = Bf[cn * 36 + laneB];
        float vn[4][3];
        loadw(xb, cn, r0, w, vn);

        #pragma unroll
        for (int p = 0; p < 9; ++p) {
            const int i = p / 3;             // compile-time (unrolled)
            const int j = p % 3;
            const float va = vv[i][j];
            const float vb = vv[i + 1][j];

            // JIT coefficient extraction: v_readlane (SALU, no wait states).
            const float a0 = rdl(cA, p * 6 + 0);
            const float a1 = rdl(cA, p * 6 + 1);
            const float a2 = rdl(cA, p * 6 + 2);
            const float a3 = rdl(cA, p * 6 + 3);
            const float a4 = rdl(cA, p * 6 + 4);
            const float a5 = rdl(cA, p * 6 + 5);
            const float b1 = rdl(cB, p * 4 + 0);
            const float b2 = rdl(cB, p * 4 + 1);
            const float b3 = rdl(cB, p * 4 + 2);
            const float b4 = rdl(cB, p * 4 + 3);

            float P0 = a5, P1 = a5;
            P0 = fmaf(P0, va, a4);  P1 = fmaf(P1, vb, a4);
            P0 = fmaf(P0, va, a3);  P1 = fmaf(P1, vb, a3);
            P0 = fmaf(P0, va, a2);  P1 = fmaf(P1, vb, a2);
            P0 = fmaf(P0, va, a1);  P1 = fmaf(P1, vb, a1);
            P0 = fmaf(P0, va, a0);  P1 = fmaf(P1, vb, a0);

            float q0 = b4, q1 = b4;
            q0 = fmaf(q0, va, b3);  q1 = fmaf(q1, vb, b3);
            q0 = fmaf(q0, va, b2);  q1 = fmaf(q1, vb, b2);
            q0 = fmaf(q0, va, b1);  q1 = fmaf(q1, vb, b1);
            q0 *= va;               q1 *= vb;

            const float d0 = 1.0f + fabsf(q0);
            const float d1 = 1.0f + fabsf(q1);
            acc0 = fmaf(P0, __builtin_amdgcn_rcpf(d0), acc0);
            acc1 = fmaf(P1, __builtin_amdgcn_rcpf(d1), acc1);
        }

        // Rotate prefetched state.
        cA = nA;  cB = nB;
        #pragma unroll
        for (int ri = 0; ri < 4; ++ri)
            #pragma unroll
            for (int j = 0; j < 3; ++j)
                vv[ri][j] = vn[ri][j];
    }

    // Reduce the two channel-halves: team 1 -> LDS, team 0 adds and stores.
    if (team == 1) {
        sRed[tp]       = acc0;
        sRed[256 + tp] = acc1;
    }
    __syncthreads();
    if (team == 0) {
        acc0 += sRed[tp];
        acc1 += sRed[256 + tp];
        float* __restrict__ of = out + ((b * COUT + f) * HH) * WW + w;
        of[r0 * WW]       = acc0;
        of[(r0 + 1) * WW] = acc1;
    }
}

extern "C" void kernel_launch(void* const* d_in, const int* in_sizes, int n_in,
                              void* d_out, int out_size, void* d_ws, size_t ws_size,
                              hipStream_t stream) {
    const float* x  = (const float*)d_in[0];
    const float* A  = (const float*)d_in[1];
    const float* Bc = (const float*)d_in[2];
    float* out = (float*)d_out;

    const int grid = BB * (HH / 8) * COUT;   // 512 blocks
    KAConv_kernel<<<grid, 512, 0, stream>>>(x, A, Bc, out);
}